// Round 12
// baseline (569.497 us; speedup 1.0000x reference)
//
#include <hip/hip_runtime.h>

#define DD 256
#define TWO_D 512
#define NLAYER 5
#define NGRAPH 256
#define BNEPS 1e-5f

typedef __attribute__((ext_vector_type(8))) _Float16 half8;
typedef __attribute__((ext_vector_type(4))) _Float16 half4;
typedef __attribute__((ext_vector_type(4))) float f32x4;

#define MFMA16 __builtin_amdgcn_mfma_f32_16x16x32_f16

// ================= fused prep: embed | wconv(frag-swizzle) | etab | pack+hist ==========
__global__ __launch_bounds__(256) void prep_kernel(
    const int* __restrict__ xf,
    const float* __restrict__ nt1, const float* __restrict__ nt2,
    const float* __restrict__ nt3, const float* __restrict__ nt4,
    const float* __restrict__ nt5, const float* __restrict__ nt6,
    _Float16* __restrict__ h16,
    const float* __restrict__ w1, const float* __restrict__ w2,
    _Float16* __restrict__ w1f, _Float16* __restrict__ w2f,
    const float* __restrict__ et1, const float* __restrict__ et2,
    const float* __restrict__ et3, const float* __restrict__ et4,
    const float* __restrict__ et5, _Float16* __restrict__ etab,
    int* __restrict__ deg,
    const int* __restrict__ ei, const int* __restrict__ ea,
    int* __restrict__ packed,
    int N, int E)
{
  const int t = threadIdx.x;
  const int b = blockIdx.x;
  const int B_EMB = N;
  const int B_WC  = 128;
  const int B_ET  = NLAYER * 33;

  if (b < B_EMB) {
    int i = b, j = t;
    int x0 = xf[i*6+0], x1 = xf[i*6+1], x2 = xf[i*6+2];
    int x3 = xf[i*6+3], x4 = xf[i*6+4], x5 = xf[i*6+5];
    float v = nt1[x0*DD+j] + nt2[x1*DD+j] + nt3[x2*DD+j]
            + nt4[x3*DD+j] + nt5[x4*DD+j] + nt6[x5*DD+j];
    h16[(size_t)i*DD + j] = (_Float16)v;
  } else if (b < B_EMB + B_WC) {
    // weights -> fp16 in MFMA fragment order: [rowblk][kseg][lane=quad*16+r15][8]
    int bid = b - B_EMB;
    int n = NLAYER * TWO_D * DD;
    for (int i = bid*256 + t; i < n; i += B_WC*256) {
      int l = i >> 17, rem = i & 131071;
      int r = rem >> 8, k = rem & 255;
      int o1 = (l<<17) + (((r>>4)<<3) + (k>>5))*512 + ((((k>>3)&3)<<4) + (r&15))*8 + (k&7);
      w1f[o1] = (_Float16)w1[i];
      int r2 = rem >> 9, k2 = rem & 511;
      int o2 = (l<<17) + (((r2>>4)<<4) + (k2>>5))*512 + ((((k2>>3)&3)<<4) + (r2&15))*8 + (k2&7);
      w2f[o2] = (_Float16)w2[i];
    }
  } else if (b < B_EMB + B_WC + B_ET) {
    int bid = b - B_EMB - B_WC;
    int l = bid / 33, c = bid % 33;
    int j = t;
    int a0 = (c==32)?4:(c&1);
    int a1 = (c==32)?0:((c>>1)&1);
    int a2 = (c==32)?0:((c>>2)&1);
    int a3 = (c==32)?0:((c>>3)&1);
    int a4 = (c==32)?0:((c>>4)&1);
    etab[((size_t)l*33 + c)*DD + j] = (_Float16)(
        et1[(l*5+a0)*DD+j] + et2[(l*4+a1)*DD+j] + et3[(l*2+a2)*DD+j]
      + et4[(l*2+a3)*DD+j] + et5[(l*2+a4)*DD+j]);
  } else {
    // pack + degree histogram (deg pre-zeroed via hipMemsetAsync)
    int bid = b - B_EMB - B_WC - B_ET;
    int e = bid*256 + t;
    if (e < E) {
      int src = ei[e];
      int dst = ei[E + e];
      int code = (ea[e*5+0]&1) | ((ea[e*5+1]&1)<<1) | ((ea[e*5+2]&1)<<2)
               | ((ea[e*5+3]&1)<<3) | ((ea[e*5+4]&1)<<4);
      packed[e] = src | (code << 16);
      atomicAdd(&deg[dst], 1);
    }
  }
}

// ================= CSR build =================
__global__ __launch_bounds__(1024) void scan_kernel(
    const int* __restrict__ deg, int* __restrict__ row_start,
    int* __restrict__ cursor, int N)
{
  __shared__ int sh[1024];
  int t = threadIdx.x;
  const int CH = (N + 1023) >> 10;
  int base = t * CH;
  int lim = N - base; if (lim < 0) lim = 0; if (lim > CH) lim = CH;
  int s = 0;
  for (int i = 0; i < lim; ++i) s += deg[base + i];
  sh[t] = s;
  __syncthreads();
  for (int off = 1; off < 1024; off <<= 1) {
    int x = (t >= off) ? sh[t - off] : 0;
    __syncthreads();
    sh[t] += x;
    __syncthreads();
  }
  int run = t ? sh[t-1] : 0;
  for (int i = 0; i < lim; ++i) {
    row_start[base+i] = run; cursor[base+i] = run;
    run += deg[base+i];
  }
  if (t == 1023) row_start[N] = sh[1023];
}

__global__ __launch_bounds__(256) void scatter_kernel(
    const int* __restrict__ ei, const int* __restrict__ packed,
    int* __restrict__ cursor, int* __restrict__ esort, int E)
{
  int e = blockIdx.x*256 + threadIdx.x;
  if (e >= E) return;
  int dst = ei[E + e];
  int pos = atomicAdd(&cursor[dst], 1);
  esort[pos] = packed[e];
}

// ========== aggregation: one wave per node, 8-edge unroll, inline BN+ReLU ==========
template<int APPLY_BN>
__global__ __launch_bounds__(256) void aggr_kernel(
    const _Float16* __restrict__ hsrc, const _Float16* __restrict__ etab_l,
    const int* __restrict__ row_start, const int* __restrict__ esort,
    const float* __restrict__ stats_prev, const float* __restrict__ g,
    const float* __restrict__ bb, float inv_n,
    _Float16* __restrict__ aggrh, int N)
{
  __shared__ __attribute__((aligned(16))) _Float16 se[33*DD];
  for (int i = threadIdx.x; i < 33*DD/8; i += 256)
    ((int4*)se)[i] = ((const int4*)etab_l)[i];
  __syncthreads();
  const int wave = threadIdx.x >> 6, lane = threadIdx.x & 63;
  const int c4 = lane << 2;
  float sc0=1.f, sc1=1.f, sc2=1.f, sc3=1.f, sh0=0.f, sh1=0.f, sh2=0.f, sh3=0.f;
  if (APPLY_BN) {
#define MKSC(k, SC, SH) { float m_ = stats_prev[c4+k]*inv_n;                      \
    float v_ = fmaxf(stats_prev[DD+c4+k]*inv_n - m_*m_, 0.f);                     \
    SC = g[c4+k]*rsqrtf(v_+BNEPS); SH = bb[c4+k] - m_*SC; }
    MKSC(0, sc0, sh0) MKSC(1, sc1, sh1) MKSC(2, sc2, sh2) MKSC(3, sc3, sh3)
#undef MKSC
  }
  const int W0 = blockIdx.x*4 + wave, NW = gridDim.x*4;

#define BNX(h4, o0, o1, o2, o3)                                           \
  { float t0_ = (float)(h4).x, t1_ = (float)(h4).y,                       \
          t2_ = (float)(h4).z, t3_ = (float)(h4).w;                       \
    if (APPLY_BN) {                                                       \
      t0_ = fmaxf(t0_*sc0 + sh0, 0.f); t1_ = fmaxf(t1_*sc1 + sh1, 0.f);  \
      t2_ = fmaxf(t2_*sc2 + sh2, 0.f); t3_ = fmaxf(t3_*sc3 + sh3, 0.f);  \
    }                                                                     \
    o0 = t0_; o1 = t1_; o2 = t2_; o3 = t3_; }
#define ACC4(hx, ex)                                                      \
  { float bx_, by_, bz_, bw_;                                             \
    BNX(hx, bx_, by_, bz_, bw_);                                          \
    ax += bx_ + (float)(ex).x; ay += by_ + (float)(ex).y;                 \
    az += bz_ + (float)(ex).z; aw += bw_ + (float)(ex).w; }

  for (int node = W0; node < N; node += NW) {
    int p  = row_start[node];
    int pe = row_start[node+1];
    const half4 hv = *(const half4*)(hsrc + (size_t)node*DD + c4);
    const half4 sv = *(const half4*)(se + 32*DD + c4);
    float ax, ay, az, aw;
    BNX(hv, ax, ay, az, aw);
    ax += (float)sv.x; ay += (float)sv.y; az += (float)sv.z; aw += (float)sv.w;
    for (; p + 8 <= pe; p += 8) {
      int pk0 = esort[p],   pk1 = esort[p+1], pk2 = esort[p+2], pk3 = esort[p+3];
      int pk4 = esort[p+4], pk5 = esort[p+5], pk6 = esort[p+6], pk7 = esort[p+7];
      const half4 a0 = *(const half4*)(hsrc + (size_t)(pk0 & 0xffff)*DD + c4);
      const half4 a1 = *(const half4*)(hsrc + (size_t)(pk1 & 0xffff)*DD + c4);
      const half4 a2 = *(const half4*)(hsrc + (size_t)(pk2 & 0xffff)*DD + c4);
      const half4 a3 = *(const half4*)(hsrc + (size_t)(pk3 & 0xffff)*DD + c4);
      const half4 a4 = *(const half4*)(hsrc + (size_t)(pk4 & 0xffff)*DD + c4);
      const half4 a5 = *(const half4*)(hsrc + (size_t)(pk5 & 0xffff)*DD + c4);
      const half4 a6 = *(const half4*)(hsrc + (size_t)(pk6 & 0xffff)*DD + c4);
      const half4 a7 = *(const half4*)(hsrc + (size_t)(pk7 & 0xffff)*DD + c4);
      const half4 e0 = *(const half4*)(se + (pk0 >> 16)*DD + c4);
      const half4 e1 = *(const half4*)(se + (pk1 >> 16)*DD + c4);
      const half4 e2 = *(const half4*)(se + (pk2 >> 16)*DD + c4);
      const half4 e3 = *(const half4*)(se + (pk3 >> 16)*DD + c4);
      const half4 e4 = *(const half4*)(se + (pk4 >> 16)*DD + c4);
      const half4 e5 = *(const half4*)(se + (pk5 >> 16)*DD + c4);
      const half4 e6 = *(const half4*)(se + (pk6 >> 16)*DD + c4);
      const half4 e7 = *(const half4*)(se + (pk7 >> 16)*DD + c4);
      ACC4(a0, e0) ACC4(a1, e1) ACC4(a2, e2) ACC4(a3, e3)
      ACC4(a4, e4) ACC4(a5, e5) ACC4(a6, e6) ACC4(a7, e7)
    }
    for (; p + 4 <= pe; p += 4) {
      int pk0 = esort[p], pk1 = esort[p+1], pk2 = esort[p+2], pk3 = esort[p+3];
      const half4 a0 = *(const half4*)(hsrc + (size_t)(pk0 & 0xffff)*DD + c4);
      const half4 a1 = *(const half4*)(hsrc + (size_t)(pk1 & 0xffff)*DD + c4);
      const half4 a2 = *(const half4*)(hsrc + (size_t)(pk2 & 0xffff)*DD + c4);
      const half4 a3 = *(const half4*)(hsrc + (size_t)(pk3 & 0xffff)*DD + c4);
      const half4 e0 = *(const half4*)(se + (pk0 >> 16)*DD + c4);
      const half4 e1 = *(const half4*)(se + (pk1 >> 16)*DD + c4);
      const half4 e2 = *(const half4*)(se + (pk2 >> 16)*DD + c4);
      const half4 e3 = *(const half4*)(se + (pk3 >> 16)*DD + c4);
      ACC4(a0, e0) ACC4(a1, e1) ACC4(a2, e2) ACC4(a3, e3)
    }
    for (; p < pe; ++p) {
      int pk = esort[p];
      const half4 hx = *(const half4*)(hsrc + (size_t)(pk & 0xffff)*DD + c4);
      const half4 ex = *(const half4*)(se + (pk >> 16)*DD + c4);
      ACC4(hx, ex)
    }
    half4 o;
    o.x = (_Float16)ax; o.y = (_Float16)ay; o.z = (_Float16)az; o.w = (_Float16)aw;
    *(half4*)(aggrh + (size_t)node*DD + c4) = o;
  }
#undef ACC4
#undef BNX
}

// ====== fused MLP v2 (proven config): 32-row tiles, 512 thr, frag-order W ======
__global__ __launch_bounds__(512) void mlp_kernel(
    const _Float16* __restrict__ A,     // [M][256] row-major
    const _Float16* __restrict__ W1f,   // fragment order
    const float* __restrict__ b1,
    const _Float16* __restrict__ W2f,   // fragment order
    const float* __restrict__ b2,
    _Float16* __restrict__ O,           // [M][256] row-major
    float* __restrict__ stats,
    int Nreal)
{
  __shared__ __attribute__((aligned(16))) _Float16 sA[32*256];  // 16 KB, XOR seg^(row&7)
  __shared__ __attribute__((aligned(16))) _Float16 sH[32*128];  // 8 KB
  const int m0 = blockIdx.x << 5;
  const int t = threadIdx.x;
  const int w = t >> 6, lane = t & 63;
  const int r15 = lane & 15, quad = lane >> 4;
  const int rx = r15 & 7;

  // ---- stage A tile (coalesced reads, swizzled LDS writes) ----
#pragma unroll
  for (int i = 0; i < 2; ++i) {
    int seg = (i << 9) + t;
    int row = seg >> 5, s = seg & 31;
    half8 v = *(const half8*)(A + (size_t)(m0 + row)*DD + (s << 3));
    *(half8*)(sA + (row << 8) + ((s ^ (row & 7)) << 3)) = v;
  }
  __syncthreads();

  f32x4 acc2[2][2] = {};
#pragma unroll 1
  for (int c = 0; c < 4; ++c) {
    // ---- phase 1: hid cols c*128 + w*16 + r15 ----
    f32x4 acc1[2] = {};
    const _Float16* W1b = W1f + (((c << 3) + w) << 12);   // rowblk (c*8+w) * 8 ks * 512
#pragma unroll
    for (int ks = 0; ks < 8; ++ks) {
      int so = (((ks << 2) + quad) ^ rx) << 3;
      half8 a0 = *(const half8*)(sA + (r15 << 8) + so);
      half8 a1 = *(const half8*)(sA + ((16 + r15) << 8) + so);
      half8 bf = *(const half8*)(W1b + (ks << 9) + (lane << 3));
      acc1[0] = MFMA16(a0, bf, acc1[0], 0, 0, 0);
      acc1[1] = MFMA16(a1, bf, acc1[1], 0, 0, 0);
    }
    {
      int colL = (w << 4) + r15;
      float bv = b1[(c << 7) + colL];
#pragma unroll
      for (int fm = 0; fm < 2; ++fm)
#pragma unroll
        for (int r = 0; r < 4; ++r) {
          int row = (fm << 4) + (quad << 2) + r;
          float v = fmaxf(acc1[fm][r] + bv, 0.f);
          sH[(row << 7) + ((((colL >> 3) ^ (row & 7)) << 3)) + (colL & 7)] = (_Float16)v;
        }
    }
    __syncthreads();
    // ---- phase 2: acc2 += hid_c @ W2[:, c*128..]^T, out cols w*32 + fn*16 + r15 ----
#pragma unroll
    for (int ks = 0; ks < 4; ++ks) {
      int so = (((ks << 2) + quad) ^ rx) << 3;
      half8 a0 = *(const half8*)(sH + (r15 << 7) + so);
      half8 a1 = *(const half8*)(sH + ((16 + r15) << 7) + so);
      int ks2 = (c << 2) + ks;
      half8 b0 = *(const half8*)(W2f + ((((w << 1) + 0) << 13)) + (ks2 << 9) + (lane << 3));
      half8 b1v = *(const half8*)(W2f + ((((w << 1) + 1) << 13)) + (ks2 << 9) + (lane << 3));
      acc2[0][0] = MFMA16(a0, b0, acc2[0][0], 0, 0, 0);
      acc2[0][1] = MFMA16(a0, b1v, acc2[0][1], 0, 0, 0);
      acc2[1][0] = MFMA16(a1, b0, acc2[1][0], 0, 0, 0);
      acc2[1][1] = MFMA16(a1, b1v, acc2[1][1], 0, 0, 0);
    }
    __syncthreads();
  }

  // ---- epilogue: bias + stats; transpose via sA; vector stores ----
#pragma unroll
  for (int fn = 0; fn < 2; ++fn) {
    int col = (w << 5) + (fn << 4) + r15;
    float bv = b2[col];
    float s1 = 0.f, s2 = 0.f;
#pragma unroll
    for (int fm = 0; fm < 2; ++fm)
#pragma unroll
      for (int r = 0; r < 4; ++r) {
        int row = (fm << 4) + (quad << 2) + r;
        float v = acc2[fm][fn][r] + bv;
        sA[(row << 8) + (((col >> 3) ^ (row & 7)) << 3) + (col & 7)] = (_Float16)v;
        if (m0 + row < Nreal) { s1 += v; s2 += v*v; }
      }
    s1 += __shfl_xor(s1, 16); s1 += __shfl_xor(s1, 32);
    s2 += __shfl_xor(s2, 16); s2 += __shfl_xor(s2, 32);
    if (lane < 16) { atomicAdd(&stats[col], s1); atomicAdd(&stats[DD + col], s2); }
  }
  __syncthreads();
#pragma unroll
  for (int i = 0; i < 2; ++i) {
    int seg = (i << 9) + t;
    int row = seg >> 5, s = seg & 31;
    half8 v = *(const half8*)(sA + (row << 8) + ((s ^ (row & 7)) << 3));
    *(half8*)(O + (size_t)(m0 + row)*DD + (s << 3)) = v;
  }
}

// ================= mean pool by (sorted) batch, inline BN+ReLU, 16-row blocks ==========
__global__ __launch_bounds__(256) void pool_kernel(
    const _Float16* __restrict__ hh16, const float* __restrict__ stats_prev,
    const float* __restrict__ g, const float* __restrict__ bb, float inv_n,
    const int* __restrict__ batch,
    float* __restrict__ hgsum, int* __restrict__ hgcnt, int N)
{
  int j = threadIdx.x;
  float m = stats_prev[j]*inv_n;
  float var = fmaxf(stats_prev[DD+j]*inv_n - m*m, 0.f);
  float sc = g[j]*rsqrtf(var + BNEPS);
  float sh = bb[j] - m*sc;
  int r0 = blockIdx.x * 16;
  int cur = -1; float acc = 0.f; int run = 0;
  for (int r = 0; r < 16; ++r) {
    int row = r0 + r;
    if (row >= N) break;
    int gg = batch[row];
    if (gg != cur) {
      if (cur >= 0) {
        atomicAdd(&hgsum[(size_t)cur*DD + j], acc);
        if (j == 0) atomicAdd(&hgcnt[cur], run);
      }
      cur = gg; acc = 0.f; run = 0;
    }
    float v = (float)hh16[(size_t)row*DD + j];
    acc += fmaxf(v*sc + sh, 0.f);
    run++;
  }
  if (cur >= 0) {
    atomicAdd(&hgsum[(size_t)cur*DD + j], acc);
    if (j == 0) atomicAdd(&hgcnt[cur], run);
  }
}

// ================= projection head GEMM with fused input transform =================
template<int MODE>
__global__ __launch_bounds__(256) void proj_gemm_kernel(
    const float* __restrict__ in, const int* __restrict__ cnt,
    const float* __restrict__ pstat_prev,
    const float* __restrict__ gprev, const float* __restrict__ bprev,
    const float* __restrict__ W,
    float* __restrict__ outb, float* __restrict__ pstat)
{
  __shared__ float sA[16][17];
  __shared__ float sB[16][17];
  int tx = threadIdx.x, ty = threadIdx.y;
  int r = blockIdx.y*16 + ty;
  int c = blockIdx.x*16 + tx;
  float acc = 0.f;
  for (int k0 = 0; k0 < DD; k0 += 16) {
    int k = k0 + tx;
    float a = in[(size_t)r*DD + k];
    if (MODE == 0) {
      a /= (float)max(cnt[r], 1);
    } else {
      float m = pstat_prev[k] * (1.0f/NGRAPH);
      float var = fmaxf(pstat_prev[DD + k] * (1.0f/NGRAPH) - m*m, 0.f);
      float sc = gprev[k] * rsqrtf(var + BNEPS);
      a = fmaxf((a - m)*sc + bprev[k], 0.f);
    }
    sA[ty][tx] = a;
    sB[ty][tx] = W[(size_t)(blockIdx.x*16 + ty)*DD + k0 + tx];
    __syncthreads();
#pragma unroll
    for (int kk = 0; kk < 16; ++kk) acc += sA[ty][kk] * sB[tx][kk];
    __syncthreads();
  }
  outb[(size_t)r*DD + c] = acc;
  sA[ty][tx] = acc; sB[ty][tx] = acc*acc;
  __syncthreads();
  for (int o = 8; o > 0; o >>= 1) {
    if (ty < o) { sA[ty][tx] += sA[ty+o][tx]; sB[ty][tx] += sB[ty+o][tx]; }
    __syncthreads();
  }
  if (ty == 0) { atomicAdd(&pstat[c], sA[0][tx]); atomicAdd(&pstat[DD + c], sB[0][tx]); }
}

// ================= output MLP with fused final BN (no relu) =================
__global__ __launch_bounds__(128) void out_kernel(
    const float* __restrict__ t2, const float* __restrict__ pstat2,
    const float* __restrict__ g2, const float* __restrict__ b2p,
    const float* __restrict__ ow1, const float* __restrict__ ob1,
    const float* __restrict__ ow2, const float* __restrict__ ob2,
    float* __restrict__ outp)
{
  __shared__ float rowv[DD];
  __shared__ float z[128];
  int r = blockIdx.x, t = threadIdx.x;
#pragma unroll
  for (int half = 0; half < 2; ++half) {
    int j = t + half*128;
    float m = pstat2[j] * (1.0f/NGRAPH);
    float var = fmaxf(pstat2[DD + j] * (1.0f/NGRAPH) - m*m, 0.f);
    float sc = g2[j] * rsqrtf(var + BNEPS);
    rowv[j] = (t2[(size_t)r*DD + j] - m)*sc + b2p[j];
  }
  __syncthreads();
  float a = ob1[t];
  for (int k = 0; k < DD; ++k) a += rowv[k] * ow1[(size_t)t*DD + k];
  z[t] = fmaxf(a, 0.f) + log1pf(expf(-fabsf(a)));   // softplus, stable
  __syncthreads();
  if (t < 2) {
    float o = ob2[t];
    for (int k = 0; k < 128; ++k) o += z[k] * ow2[t*128 + k];
    outp[r*2 + t] = o;
  }
}

// ================= host launcher =================
extern "C" void kernel_launch(void* const* d_in, const int* in_sizes, int n_in,
                              void* d_out, int out_size, void* d_ws, size_t ws_size,
                              hipStream_t stream)
{
  const int* x_feats = (const int*)d_in[0];
  const int* ei      = (const int*)d_in[1];
  const int* ea      = (const int*)d_in[2];
  const int* batch   = (const int*)d_in[3];
  const float* nt1 = (const float*)d_in[4];
  const float* nt2 = (const float*)d_in[5];
  const float* nt3 = (const float*)d_in[6];
  const float* nt4 = (const float*)d_in[7];
  const float* nt5 = (const float*)d_in[8];
  const float* nt6 = (const float*)d_in[9];
  const float* et1 = (const float*)d_in[10];
  const float* et2 = (const float*)d_in[11];
  const float* et3 = (const float*)d_in[12];
  const float* et4 = (const float*)d_in[13];
  const float* et5 = (const float*)d_in[14];
  const float* w1  = (const float*)d_in[15];
  const float* b1  = (const float*)d_in[16];
  const float* w2  = (const float*)d_in[17];
  const float* b2  = (const float*)d_in[18];
  const float* bng = (const float*)d_in[19];
  const float* bnb = (const float*)d_in[20];
  const float* pw  = (const float*)d_in[21];
  const float* pg  = (const float*)d_in[22];
  const float* pb  = (const float*)d_in[23];
  const float* ow1 = (const float*)d_in[24];
  const float* ob1 = (const float*)d_in[25];
  const float* ow2 = (const float*)d_in[26];
  const float* ob2 = (const float*)d_in[27];

  const int N = in_sizes[0] / 6;        // 20000
  const int E = in_sizes[1] / 2;        // 320000
  const int Mp = ((N + 31) >> 5) << 5;  // 32-row tiles: 20000 exactly

  unsigned char* wp = (unsigned char*)d_ws;
  size_t off = 0;
  auto carve = [&](size_t bytes) -> void* {
    void* p = wp + off;
    off += (bytes + 255) & ~(size_t)255;
    return p;
  };

  _Float16* h16      = (_Float16*)carve((size_t)N * DD * 2);
  _Float16* aggrh    = (_Float16*)carve((size_t)Mp * DD * 2);
  _Float16* hh16     = (_Float16*)carve((size_t)Mp * DD * 2);
  _Float16* w1f      = (_Float16*)carve((size_t)NLAYER * TWO_D * DD * 2);
  _Float16* w2f      = (_Float16*)carve((size_t)NLAYER * TWO_D * DD * 2);
  _Float16* etabg    = (_Float16*)carve((size_t)NLAYER * 33 * DD * 2);
  int* deg           = (int*)carve((size_t)N * 4);
  int* row_start     = (int*)carve((size_t)(N + 1) * 4);
  int* cursor        = (int*)carve((size_t)N * 4);
  int* packed        = (int*)carve((size_t)E * 4);
  int* esort         = (int*)carve((size_t)E * 4);
  // ---- contiguous zero region (single memset) ----
  float* stats       = (float*)carve((size_t)NLAYER * 2 * DD * 4);   // 10240 B
  float* hgsum       = (float*)carve((size_t)NGRAPH * DD * 4);       // 262144 B
  int* hgcnt         = (int*)carve((size_t)NGRAPH * 4);              // 1024 B
  float* pstats      = (float*)carve(3 * 2 * DD * 4);                // 6144 B
  const size_t ZR_BYTES = 10240 + 262144 + 1024 + 6144;
  // ---- end zero region ----
  float* hgA         = (float*)carve((size_t)NGRAPH * DD * 4);
  float* hgB         = (float*)carve((size_t)NGRAPH * DD * 4);
  float* t0c         = (float*)carve((size_t)NGRAPH * DD * 4);
  (void)ws_size; (void)n_in; (void)out_size;

  const int EB = (E + 255) / 256;
  const float inv_n = 1.0f / (float)N;

  hipMemsetAsync(deg, 0, (size_t)N * 4, stream);
  hipMemsetAsync(stats, 0, ZR_BYTES, stream);

  const int PREP_BLOCKS = N + 128 + NLAYER*33 + EB;
  prep_kernel<<<PREP_BLOCKS, 256, 0, stream>>>(
      x_feats, nt1, nt2, nt3, nt4, nt5, nt6, h16,
      w1, w2, w1f, w2f,
      et1, et2, et3, et4, et5, etabg,
      deg, ei, ea, packed, N, E);
  scan_kernel<<<1, 1024, 0, stream>>>(deg, row_start, cursor, N);
  scatter_kernel<<<EB, 256, 0, stream>>>(ei, packed, cursor, esort, E);

  const int MB = Mp >> 5;   // 32-row MLP blocks (625)
  for (int l = 0; l < NLAYER; ++l) {
    float* st_prev = stats + (size_t)(l-1)*2*DD;
    float* st_cur  = stats + (size_t)l*2*DD;
    if (l == 0) {
      aggr_kernel<0><<<2048, 256, 0, stream>>>(h16, etabg, row_start, esort,
                                               nullptr, nullptr, nullptr, inv_n,
                                               aggrh, N);
    } else {
      aggr_kernel<1><<<2048, 256, 0, stream>>>(hh16, etabg + (size_t)l*33*DD,
                                               row_start, esort,
                                               st_prev, bng + (l-1)*DD, bnb + (l-1)*DD,
                                               inv_n, aggrh, N);
    }
    mlp_kernel<<<MB, 512, 0, stream>>>(
        aggrh, w1f + ((size_t)l << 17), b1 + l*TWO_D,
        w2f + ((size_t)l << 17), b2 + l*DD,
        hh16, st_cur, N);
  }

  pool_kernel<<<(N + 15) / 16, 256, 0, stream>>>(
      hh16, stats + (size_t)(NLAYER-1)*2*DD, bng + (NLAYER-1)*DD, bnb + (NLAYER-1)*DD,
      inv_n, batch, hgsum, hgcnt, N);

  dim3 pgrid(16, 16), pblk(16, 16);
  proj_gemm_kernel<0><<<pgrid, pblk, 0, stream>>>(
      hgsum, hgcnt, nullptr, nullptr, nullptr,
      pw + 0*DD*DD, hgA, pstats + 0*2*DD);
  proj_gemm_kernel<1><<<pgrid, pblk, 0, stream>>>(
      hgA, nullptr, pstats + 0*2*DD, pg + 0*DD, pb + 0*DD,
      pw + 1*DD*DD, hgB, pstats + 1*2*DD);
  proj_gemm_kernel<1><<<pgrid, pblk, 0, stream>>>(
      hgB, nullptr, pstats + 1*2*DD, pg + 1*DD, pb + 1*DD,
      pw + 2*DD*DD, t0c, pstats + 2*2*DD);
  out_kernel<<<NGRAPH, 128, 0, stream>>>(
      t0c, pstats + 2*2*DD, pg + 2*DD, pb + 2*DD,
      ow1, ob1, ow2, ob2, (float*)d_out);
}

// Round 13
// 541.242 us; speedup vs baseline: 1.0522x; 1.0522x over previous
//
#include <hip/hip_runtime.h>

#define DD 256
#define TWO_D 512
#define NLAYER 5
#define NGRAPH 256
#define BNEPS 1e-5f

typedef __attribute__((ext_vector_type(8))) _Float16 half8;
typedef __attribute__((ext_vector_type(4))) _Float16 half4;
typedef __attribute__((ext_vector_type(4))) float f32x4;

#define MFMA16 __builtin_amdgcn_mfma_f32_16x16x32_f16

// ================= fused prep: embed | wconv(frag-swizzle) | etab | pack+hist ==========
__global__ __launch_bounds__(256) void prep_kernel(
    const int* __restrict__ xf,
    const float* __restrict__ nt1, const float* __restrict__ nt2,
    const float* __restrict__ nt3, const float* __restrict__ nt4,
    const float* __restrict__ nt5, const float* __restrict__ nt6,
    _Float16* __restrict__ h16,
    const float* __restrict__ w1, const float* __restrict__ w2,
    _Float16* __restrict__ w1f, _Float16* __restrict__ w2f,
    const float* __restrict__ et1, const float* __restrict__ et2,
    const float* __restrict__ et3, const float* __restrict__ et4,
    const float* __restrict__ et5, _Float16* __restrict__ etab,
    int* __restrict__ deg,
    const int* __restrict__ ei, const int* __restrict__ ea,
    int* __restrict__ packed,
    int N, int E)
{
  const int t = threadIdx.x;
  const int b = blockIdx.x;
  const int B_EMB = N;
  const int B_WC  = 128;
  const int B_ET  = NLAYER * 33;

  if (b < B_EMB) {
    int i = b, j = t;
    int x0 = xf[i*6+0], x1 = xf[i*6+1], x2 = xf[i*6+2];
    int x3 = xf[i*6+3], x4 = xf[i*6+4], x5 = xf[i*6+5];
    float v = nt1[x0*DD+j] + nt2[x1*DD+j] + nt3[x2*DD+j]
            + nt4[x3*DD+j] + nt5[x4*DD+j] + nt6[x5*DD+j];
    h16[(size_t)i*DD + j] = (_Float16)v;
  } else if (b < B_EMB + B_WC) {
    // weights -> fp16 in MFMA fragment order: [rowblk][kseg][lane=quad*16+r15][8]
    int bid = b - B_EMB;
    int n = NLAYER * TWO_D * DD;
    for (int i = bid*256 + t; i < n; i += B_WC*256) {
      int l = i >> 17, rem = i & 131071;
      int r = rem >> 8, k = rem & 255;
      int o1 = (l<<17) + (((r>>4)<<3) + (k>>5))*512 + ((((k>>3)&3)<<4) + (r&15))*8 + (k&7);
      w1f[o1] = (_Float16)w1[i];
      int r2 = rem >> 9, k2 = rem & 511;
      int o2 = (l<<17) + (((r2>>4)<<4) + (k2>>5))*512 + ((((k2>>3)&3)<<4) + (r2&15))*8 + (k2&7);
      w2f[o2] = (_Float16)w2[i];
    }
  } else if (b < B_EMB + B_WC + B_ET) {
    int bid = b - B_EMB - B_WC;
    int l = bid / 33, c = bid % 33;
    int j = t;
    int a0 = (c==32)?4:(c&1);
    int a1 = (c==32)?0:((c>>1)&1);
    int a2 = (c==32)?0:((c>>2)&1);
    int a3 = (c==32)?0:((c>>3)&1);
    int a4 = (c==32)?0:((c>>4)&1);
    etab[((size_t)l*33 + c)*DD + j] = (_Float16)(
        et1[(l*5+a0)*DD+j] + et2[(l*4+a1)*DD+j] + et3[(l*2+a2)*DD+j]
      + et4[(l*2+a3)*DD+j] + et5[(l*2+a4)*DD+j]);
  } else {
    // pack + degree histogram (deg pre-zeroed via hipMemsetAsync)
    int bid = b - B_EMB - B_WC - B_ET;
    int e = bid*256 + t;
    if (e < E) {
      int src = ei[e];
      int dst = ei[E + e];
      int code = (ea[e*5+0]&1) | ((ea[e*5+1]&1)<<1) | ((ea[e*5+2]&1)<<2)
               | ((ea[e*5+3]&1)<<3) | ((ea[e*5+4]&1)<<4);
      packed[e] = src | (code << 16);
      atomicAdd(&deg[dst], 1);
    }
  }
}

// ================= CSR build =================
__global__ __launch_bounds__(1024) void scan_kernel(
    const int* __restrict__ deg, int* __restrict__ row_start,
    int* __restrict__ cursor, int N)
{
  __shared__ int sh[1024];
  int t = threadIdx.x;
  const int CH = (N + 1023) >> 10;
  int base = t * CH;
  int lim = N - base; if (lim < 0) lim = 0; if (lim > CH) lim = CH;
  int s = 0;
  for (int i = 0; i < lim; ++i) s += deg[base + i];
  sh[t] = s;
  __syncthreads();
  for (int off = 1; off < 1024; off <<= 1) {
    int x = (t >= off) ? sh[t - off] : 0;
    __syncthreads();
    sh[t] += x;
    __syncthreads();
  }
  int run = t ? sh[t-1] : 0;
  for (int i = 0; i < lim; ++i) {
    row_start[base+i] = run; cursor[base+i] = run;
    run += deg[base+i];
  }
  if (t == 1023) row_start[N] = sh[1023];
}

__global__ __launch_bounds__(256) void scatter_kernel(
    const int* __restrict__ ei, const int* __restrict__ packed,
    int* __restrict__ cursor, int* __restrict__ esort, int E)
{
  int e = blockIdx.x*256 + threadIdx.x;
  if (e >= E) return;
  int dst = ei[E + e];
  int pos = atomicAdd(&cursor[dst], 1);
  esort[pos] = packed[e];
}

// ================= aggregation: one wave per node, inline BN+ReLU =================
template<int APPLY_BN>
__global__ __launch_bounds__(256) void aggr_kernel(
    const _Float16* __restrict__ hsrc, const _Float16* __restrict__ etab_l,
    const int* __restrict__ row_start, const int* __restrict__ esort,
    const float* __restrict__ stats_prev, const float* __restrict__ g,
    const float* __restrict__ bb, float inv_n,
    _Float16* __restrict__ aggrh, int N)
{
  __shared__ __attribute__((aligned(16))) _Float16 se[33*DD];
  for (int i = threadIdx.x; i < 33*DD/8; i += 256)
    ((int4*)se)[i] = ((const int4*)etab_l)[i];
  __syncthreads();
  const int wave = threadIdx.x >> 6, lane = threadIdx.x & 63;
  const int c4 = lane << 2;
  float sc0=1.f, sc1=1.f, sc2=1.f, sc3=1.f, sh0=0.f, sh1=0.f, sh2=0.f, sh3=0.f;
  if (APPLY_BN) {
#define MKSC(k, SC, SH) { float m_ = stats_prev[c4+k]*inv_n;                      \
    float v_ = fmaxf(stats_prev[DD+c4+k]*inv_n - m_*m_, 0.f);                     \
    SC = g[c4+k]*rsqrtf(v_+BNEPS); SH = bb[c4+k] - m_*SC; }
    MKSC(0, sc0, sh0) MKSC(1, sc1, sh1) MKSC(2, sc2, sh2) MKSC(3, sc3, sh3)
#undef MKSC
  }
  const int W0 = blockIdx.x*4 + wave, NW = gridDim.x*4;

#define BNX(h4, o0, o1, o2, o3)                                           \
  { float t0_ = (float)(h4).x, t1_ = (float)(h4).y,                       \
          t2_ = (float)(h4).z, t3_ = (float)(h4).w;                       \
    if (APPLY_BN) {                                                       \
      t0_ = fmaxf(t0_*sc0 + sh0, 0.f); t1_ = fmaxf(t1_*sc1 + sh1, 0.f);  \
      t2_ = fmaxf(t2_*sc2 + sh2, 0.f); t3_ = fmaxf(t3_*sc3 + sh3, 0.f);  \
    }                                                                     \
    o0 = t0_; o1 = t1_; o2 = t2_; o3 = t3_; }

  for (int node = W0; node < N; node += NW) {
    int p  = row_start[node];
    int pe = row_start[node+1];
    const half4 hv = *(const half4*)(hsrc + (size_t)node*DD + c4);
    const half4 sv = *(const half4*)(se + 32*DD + c4);
    float ax, ay, az, aw;
    BNX(hv, ax, ay, az, aw);
    ax += (float)sv.x; ay += (float)sv.y; az += (float)sv.z; aw += (float)sv.w;
    for (; p + 4 <= pe; p += 4) {
      int pk0 = esort[p], pk1 = esort[p+1], pk2 = esort[p+2], pk3 = esort[p+3];
      const half4 h0 = *(const half4*)(hsrc + (size_t)(pk0 & 0xffff)*DD + c4);
      const half4 h1 = *(const half4*)(hsrc + (size_t)(pk1 & 0xffff)*DD + c4);
      const half4 h2 = *(const half4*)(hsrc + (size_t)(pk2 & 0xffff)*DD + c4);
      const half4 h3 = *(const half4*)(hsrc + (size_t)(pk3 & 0xffff)*DD + c4);
      const half4 e0 = *(const half4*)(se + (pk0 >> 16)*DD + c4);
      const half4 e1 = *(const half4*)(se + (pk1 >> 16)*DD + c4);
      const half4 e2 = *(const half4*)(se + (pk2 >> 16)*DD + c4);
      const half4 e3 = *(const half4*)(se + (pk3 >> 16)*DD + c4);
      float b0x,b0y,b0z,b0w, b1x,b1y,b1z,b1w, b2x,b2y,b2z,b2w, b3x,b3y,b3z,b3w;
      BNX(h0, b0x,b0y,b0z,b0w); BNX(h1, b1x,b1y,b1z,b1w);
      BNX(h2, b2x,b2y,b2z,b2w); BNX(h3, b3x,b3y,b3z,b3w);
      ax += (b0x+(float)e0.x) + (b1x+(float)e1.x) + (b2x+(float)e2.x) + (b3x+(float)e3.x);
      ay += (b0y+(float)e0.y) + (b1y+(float)e1.y) + (b2y+(float)e2.y) + (b3y+(float)e3.y);
      az += (b0z+(float)e0.z) + (b1z+(float)e1.z) + (b2z+(float)e2.z) + (b3z+(float)e3.z);
      aw += (b0w+(float)e0.w) + (b1w+(float)e1.w) + (b2w+(float)e2.w) + (b3w+(float)e3.w);
    }
    for (; p < pe; ++p) {
      int pk = esort[p];
      const half4 hx = *(const half4*)(hsrc + (size_t)(pk & 0xffff)*DD + c4);
      const half4 ex = *(const half4*)(se + (pk >> 16)*DD + c4);
      float bx, by, bz, bw;
      BNX(hx, bx, by, bz, bw);
      ax += bx + (float)ex.x; ay += by + (float)ex.y;
      az += bz + (float)ex.z; aw += bw + (float)ex.w;
    }
    half4 o;
    o.x = (_Float16)ax; o.y = (_Float16)ay; o.z = (_Float16)az; o.w = (_Float16)aw;
    *(half4*)(aggrh + (size_t)node*DD + c4) = o;
  }
#undef BNX
}

// ====== fused MLP v2 (proven 542µs config): 32-row tiles, 512 thr, frag-order W ======
__global__ __launch_bounds__(512) void mlp_kernel(
    const _Float16* __restrict__ A,     // [M][256] row-major
    const _Float16* __restrict__ W1f,   // fragment order
    const float* __restrict__ b1,
    const _Float16* __restrict__ W2f,   // fragment order
    const float* __restrict__ b2,
    _Float16* __restrict__ O,           // [M][256] row-major
    float* __restrict__ stats,
    int Nreal)
{
  __shared__ __attribute__((aligned(16))) _Float16 sA[32*256];  // 16 KB, XOR seg^(row&7)
  __shared__ __attribute__((aligned(16))) _Float16 sH[32*128];  // 8 KB
  const int m0 = blockIdx.x << 5;
  const int t = threadIdx.x;
  const int w = t >> 6, lane = t & 63;
  const int r15 = lane & 15, quad = lane >> 4;
  const int rx = r15 & 7;

  // ---- stage A tile (coalesced reads, swizzled LDS writes) ----
#pragma unroll
  for (int i = 0; i < 2; ++i) {
    int seg = (i << 9) + t;
    int row = seg >> 5, s = seg & 31;
    half8 v = *(const half8*)(A + (size_t)(m0 + row)*DD + (s << 3));
    *(half8*)(sA + (row << 8) + ((s ^ (row & 7)) << 3)) = v;
  }
  __syncthreads();

  f32x4 acc2[2][2] = {};
#pragma unroll 1
  for (int c = 0; c < 4; ++c) {
    // ---- phase 1: hid cols c*128 + w*16 + r15 ----
    f32x4 acc1[2] = {};
    const _Float16* W1b = W1f + (((c << 3) + w) << 12);   // rowblk (c*8+w) * 8 ks * 512
#pragma unroll
    for (int ks = 0; ks < 8; ++ks) {
      int so = (((ks << 2) + quad) ^ rx) << 3;
      half8 a0 = *(const half8*)(sA + (r15 << 8) + so);
      half8 a1 = *(const half8*)(sA + ((16 + r15) << 8) + so);
      half8 bf = *(const half8*)(W1b + (ks << 9) + (lane << 3));
      acc1[0] = MFMA16(a0, bf, acc1[0], 0, 0, 0);
      acc1[1] = MFMA16(a1, bf, acc1[1], 0, 0, 0);
    }
    {
      int colL = (w << 4) + r15;
      float bv = b1[(c << 7) + colL];
#pragma unroll
      for (int fm = 0; fm < 2; ++fm)
#pragma unroll
        for (int r = 0; r < 4; ++r) {
          int row = (fm << 4) + (quad << 2) + r;
          float v = fmaxf(acc1[fm][r] + bv, 0.f);
          sH[(row << 7) + ((((colL >> 3) ^ (row & 7)) << 3)) + (colL & 7)] = (_Float16)v;
        }
    }
    __syncthreads();
    // ---- phase 2: acc2 += hid_c @ W2[:, c*128..]^T, out cols w*32 + fn*16 + r15 ----
#pragma unroll
    for (int ks = 0; ks < 4; ++ks) {
      int so = (((ks << 2) + quad) ^ rx) << 3;
      half8 a0 = *(const half8*)(sH + (r15 << 7) + so);
      half8 a1 = *(const half8*)(sH + ((16 + r15) << 7) + so);
      int ks2 = (c << 2) + ks;
      half8 b0 = *(const half8*)(W2f + ((((w << 1) + 0) << 13)) + (ks2 << 9) + (lane << 3));
      half8 b1v = *(const half8*)(W2f + ((((w << 1) + 1) << 13)) + (ks2 << 9) + (lane << 3));
      acc2[0][0] = MFMA16(a0, b0, acc2[0][0], 0, 0, 0);
      acc2[0][1] = MFMA16(a0, b1v, acc2[0][1], 0, 0, 0);
      acc2[1][0] = MFMA16(a1, b0, acc2[1][0], 0, 0, 0);
      acc2[1][1] = MFMA16(a1, b1v, acc2[1][1], 0, 0, 0);
    }
    __syncthreads();
  }

  // ---- epilogue: bias + stats; transpose via sA; vector stores ----
#pragma unroll
  for (int fn = 0; fn < 2; ++fn) {
    int col = (w << 5) + (fn << 4) + r15;
    float bv = b2[col];
    float s1 = 0.f, s2 = 0.f;
#pragma unroll
    for (int fm = 0; fm < 2; ++fm)
#pragma unroll
      for (int r = 0; r < 4; ++r) {
        int row = (fm << 4) + (quad << 2) + r;
        float v = acc2[fm][fn][r] + bv;
        sA[(row << 8) + (((col >> 3) ^ (row & 7)) << 3) + (col & 7)] = (_Float16)v;
        if (m0 + row < Nreal) { s1 += v; s2 += v*v; }
      }
    s1 += __shfl_xor(s1, 16); s1 += __shfl_xor(s1, 32);
    s2 += __shfl_xor(s2, 16); s2 += __shfl_xor(s2, 32);
    if (lane < 16) { atomicAdd(&stats[col], s1); atomicAdd(&stats[DD + col], s2); }
  }
  __syncthreads();
#pragma unroll
  for (int i = 0; i < 2; ++i) {
    int seg = (i << 9) + t;
    int row = seg >> 5, s = seg & 31;
    half8 v = *(const half8*)(sA + (row << 8) + ((s ^ (row & 7)) << 3));
    *(half8*)(O + (size_t)(m0 + row)*DD + (s << 3)) = v;
  }
}

// ================= mean pool by (sorted) batch, inline BN+ReLU, 16-row blocks ==========
__global__ __launch_bounds__(256) void pool_kernel(
    const _Float16* __restrict__ hh16, const float* __restrict__ stats_prev,
    const float* __restrict__ g, const float* __restrict__ bb, float inv_n,
    const int* __restrict__ batch,
    float* __restrict__ hgsum, int* __restrict__ hgcnt, int N)
{
  int j = threadIdx.x;
  float m = stats_prev[j]*inv_n;
  float var = fmaxf(stats_prev[DD+j]*inv_n - m*m, 0.f);
  float sc = g[j]*rsqrtf(var + BNEPS);
  float sh = bb[j] - m*sc;
  int r0 = blockIdx.x * 16;
  int cur = -1; float acc = 0.f; int run = 0;
  for (int r = 0; r < 16; ++r) {
    int row = r0 + r;
    if (row >= N) break;
    int gg = batch[row];
    if (gg != cur) {
      if (cur >= 0) {
        atomicAdd(&hgsum[(size_t)cur*DD + j], acc);
        if (j == 0) atomicAdd(&hgcnt[cur], run);
      }
      cur = gg; acc = 0.f; run = 0;
    }
    float v = (float)hh16[(size_t)row*DD + j];
    acc += fmaxf(v*sc + sh, 0.f);
    run++;
  }
  if (cur >= 0) {
    atomicAdd(&hgsum[(size_t)cur*DD + j], acc);
    if (j == 0) atomicAdd(&hgcnt[cur], run);
  }
}

// ================= projection head GEMM with fused input transform =================
template<int MODE>
__global__ __launch_bounds__(256) void proj_gemm_kernel(
    const float* __restrict__ in, const int* __restrict__ cnt,
    const float* __restrict__ pstat_prev,
    const float* __restrict__ gprev, const float* __restrict__ bprev,
    const float* __restrict__ W,
    float* __restrict__ outb, float* __restrict__ pstat)
{
  __shared__ float sA[16][17];
  __shared__ float sB[16][17];
  int tx = threadIdx.x, ty = threadIdx.y;
  int r = blockIdx.y*16 + ty;
  int c = blockIdx.x*16 + tx;
  float acc = 0.f;
  for (int k0 = 0; k0 < DD; k0 += 16) {
    int k = k0 + tx;
    float a = in[(size_t)r*DD + k];
    if (MODE == 0) {
      a /= (float)max(cnt[r], 1);
    } else {
      float m = pstat_prev[k] * (1.0f/NGRAPH);
      float var = fmaxf(pstat_prev[DD + k] * (1.0f/NGRAPH) - m*m, 0.f);
      float sc = gprev[k] * rsqrtf(var + BNEPS);
      a = fmaxf((a - m)*sc + bprev[k], 0.f);
    }
    sA[ty][tx] = a;
    sB[ty][tx] = W[(size_t)(blockIdx.x*16 + ty)*DD + k0 + tx];
    __syncthreads();
#pragma unroll
    for (int kk = 0; kk < 16; ++kk) acc += sA[ty][kk] * sB[tx][kk];
    __syncthreads();
  }
  outb[(size_t)r*DD + c] = acc;
  sA[ty][tx] = acc; sB[ty][tx] = acc*acc;
  __syncthreads();
  for (int o = 8; o > 0; o >>= 1) {
    if (ty < o) { sA[ty][tx] += sA[ty+o][tx]; sB[ty][tx] += sB[ty+o][tx]; }
    __syncthreads();
  }
  if (ty == 0) { atomicAdd(&pstat[c], sA[0][tx]); atomicAdd(&pstat[DD + c], sB[0][tx]); }
}

// ================= output MLP with fused final BN (no relu) =================
__global__ __launch_bounds__(128) void out_kernel(
    const float* __restrict__ t2, const float* __restrict__ pstat2,
    const float* __restrict__ g2, const float* __restrict__ b2p,
    const float* __restrict__ ow1, const float* __restrict__ ob1,
    const float* __restrict__ ow2, const float* __restrict__ ob2,
    float* __restrict__ outp)
{
  __shared__ float rowv[DD];
  __shared__ float z[128];
  int r = blockIdx.x, t = threadIdx.x;
#pragma unroll
  for (int half = 0; half < 2; ++half) {
    int j = t + half*128;
    float m = pstat2[j] * (1.0f/NGRAPH);
    float var = fmaxf(pstat2[DD + j] * (1.0f/NGRAPH) - m*m, 0.f);
    float sc = g2[j] * rsqrtf(var + BNEPS);
    rowv[j] = (t2[(size_t)r*DD + j] - m)*sc + b2p[j];
  }
  __syncthreads();
  float a = ob1[t];
  for (int k = 0; k < DD; ++k) a += rowv[k] * ow1[(size_t)t*DD + k];
  z[t] = fmaxf(a, 0.f) + log1pf(expf(-fabsf(a)));   // softplus, stable
  __syncthreads();
  if (t < 2) {
    float o = ob2[t];
    for (int k = 0; k < 128; ++k) o += z[k] * ow2[t*128 + k];
    outp[r*2 + t] = o;
  }
}

// ================= host launcher =================
extern "C" void kernel_launch(void* const* d_in, const int* in_sizes, int n_in,
                              void* d_out, int out_size, void* d_ws, size_t ws_size,
                              hipStream_t stream)
{
  const int* x_feats = (const int*)d_in[0];
  const int* ei      = (const int*)d_in[1];
  const int* ea      = (const int*)d_in[2];
  const int* batch   = (const int*)d_in[3];
  const float* nt1 = (const float*)d_in[4];
  const float* nt2 = (const float*)d_in[5];
  const float* nt3 = (const float*)d_in[6];
  const float* nt4 = (const float*)d_in[7];
  const float* nt5 = (const float*)d_in[8];
  const float* nt6 = (const float*)d_in[9];
  const float* et1 = (const float*)d_in[10];
  const float* et2 = (const float*)d_in[11];
  const float* et3 = (const float*)d_in[12];
  const float* et4 = (const float*)d_in[13];
  const float* et5 = (const float*)d_in[14];
  const float* w1  = (const float*)d_in[15];
  const float* b1  = (const float*)d_in[16];
  const float* w2  = (const float*)d_in[17];
  const float* b2  = (const float*)d_in[18];
  const float* bng = (const float*)d_in[19];
  const float* bnb = (const float*)d_in[20];
  const float* pw  = (const float*)d_in[21];
  const float* pg  = (const float*)d_in[22];
  const float* pb  = (const float*)d_in[23];
  const float* ow1 = (const float*)d_in[24];
  const float* ob1 = (const float*)d_in[25];
  const float* ow2 = (const float*)d_in[26];
  const float* ob2 = (const float*)d_in[27];

  const int N = in_sizes[0] / 6;        // 20000
  const int E = in_sizes[1] / 2;        // 320000
  const int Mp = ((N + 31) >> 5) << 5;  // 32-row tiles: 20000 exactly

  unsigned char* wp = (unsigned char*)d_ws;
  size_t off = 0;
  auto carve = [&](size_t bytes) -> void* {
    void* p = wp + off;
    off += (bytes + 255) & ~(size_t)255;
    return p;
  };

  _Float16* h16      = (_Float16*)carve((size_t)N * DD * 2);
  _Float16* aggrh    = (_Float16*)carve((size_t)Mp * DD * 2);
  _Float16* hh16     = (_Float16*)carve((size_t)Mp * DD * 2);
  _Float16* w1f      = (_Float16*)carve((size_t)NLAYER * TWO_D * DD * 2);
  _Float16* w2f      = (_Float16*)carve((size_t)NLAYER * TWO_D * DD * 2);
  _Float16* etabg    = (_Float16*)carve((size_t)NLAYER * 33 * DD * 2);
  int* deg           = (int*)carve((size_t)N * 4);
  int* row_start     = (int*)carve((size_t)(N + 1) * 4);
  int* cursor        = (int*)carve((size_t)N * 4);
  int* packed        = (int*)carve((size_t)E * 4);
  int* esort         = (int*)carve((size_t)E * 4);
  // ---- contiguous zero region (single memset) ----
  float* stats       = (float*)carve((size_t)NLAYER * 2 * DD * 4);   // 10240 B
  float* hgsum       = (float*)carve((size_t)NGRAPH * DD * 4);       // 262144 B
  int* hgcnt         = (int*)carve((size_t)NGRAPH * 4);              // 1024 B
  float* pstats      = (float*)carve(3 * 2 * DD * 4);                // 6144 B
  const size_t ZR_BYTES = 10240 + 262144 + 1024 + 6144;
  // ---- end zero region ----
  float* hgA         = (float*)carve((size_t)NGRAPH * DD * 4);
  float* hgB         = (float*)carve((size_t)NGRAPH * DD * 4);
  float* t0c         = (float*)carve((size_t)NGRAPH * DD * 4);
  (void)ws_size; (void)n_in; (void)out_size;

  const int EB = (E + 255) / 256;
  const float inv_n = 1.0f / (float)N;

  hipMemsetAsync(deg, 0, (size_t)N * 4, stream);
  hipMemsetAsync(stats, 0, ZR_BYTES, stream);

  const int PREP_BLOCKS = N + 128 + NLAYER*33 + EB;
  prep_kernel<<<PREP_BLOCKS, 256, 0, stream>>>(
      x_feats, nt1, nt2, nt3, nt4, nt5, nt6, h16,
      w1, w2, w1f, w2f,
      et1, et2, et3, et4, et5, etabg,
      deg, ei, ea, packed, N, E);
  scan_kernel<<<1, 1024, 0, stream>>>(deg, row_start, cursor, N);
  scatter_kernel<<<EB, 256, 0, stream>>>(ei, packed, cursor, esort, E);

  const int MB = Mp >> 5;   // 32-row MLP blocks (625)
  for (int l = 0; l < NLAYER; ++l) {
    float* st_prev = stats + (size_t)(l-1)*2*DD;
    float* st_cur  = stats + (size_t)l*2*DD;
    if (l == 0) {
      aggr_kernel<0><<<2048, 256, 0, stream>>>(h16, etabg, row_start, esort,
                                               nullptr, nullptr, nullptr, inv_n,
                                               aggrh, N);
    } else {
      aggr_kernel<1><<<2048, 256, 0, stream>>>(hh16, etabg + (size_t)l*33*DD,
                                               row_start, esort,
                                               st_prev, bng + (l-1)*DD, bnb + (l-1)*DD,
                                               inv_n, aggrh, N);
    }
    mlp_kernel<<<MB, 512, 0, stream>>>(
        aggrh, w1f + ((size_t)l << 17), b1 + l*TWO_D,
        w2f + ((size_t)l << 17), b2 + l*DD,
        hh16, st_cur, N);
  }

  pool_kernel<<<(N + 15) / 16, 256, 0, stream>>>(
      hh16, stats + (size_t)(NLAYER-1)*2*DD, bng + (NLAYER-1)*DD, bnb + (NLAYER-1)*DD,
      inv_n, batch, hgsum, hgcnt, N);

  dim3 pgrid(16, 16), pblk(16, 16);
  proj_gemm_kernel<0><<<pgrid, pblk, 0, stream>>>(
      hgsum, hgcnt, nullptr, nullptr, nullptr,
      pw + 0*DD*DD, hgA, pstats + 0*2*DD);
  proj_gemm_kernel<1><<<pgrid, pblk, 0, stream>>>(
      hgA, nullptr, pstats + 0*2*DD, pg + 0*DD, pb + 0*DD,
      pw + 1*DD*DD, hgB, pstats + 1*2*DD);
  proj_gemm_kernel<1><<<pgrid, pblk, 0, stream>>>(
      hgB, nullptr, pstats + 1*2*DD, pg + 1*DD, pb + 1*DD,
      pw + 2*DD*DD, t0c, pstats + 2*2*DD);
  out_kernel<<<NGRAPH, 128, 0, stream>>>(
      t0c, pstats + 2*2*DD, pg + 2*DD, pb + 2*DD,
      ow1, ob1, ow2, ob2, (float*)d_out);
}